// Round 15
// baseline (441.693 us; speedup 1.0000x reference)
//
#include <hip/hip_runtime.h>

#define HID   15
#define TMAIN 1024
#define FUT   64
#define OUTW  (TMAIN + FUT)   // 1088

typedef _Float16 v2h   __attribute__((ext_vector_type(2)));
typedef _Float16 v8h   __attribute__((ext_vector_type(8)));
typedef float    f32x4 __attribute__((ext_vector_type(4)));
typedef int      i32x4 __attribute__((ext_vector_type(4)));

__device__ __forceinline__ float rcp_(float x)  { return __builtin_amdgcn_rcpf(x); }
__device__ __forceinline__ float exp2_(float x) { return __builtin_amdgcn_exp2f(x); }

template<int I> struct ic { static constexpr int v = I; };
template<int J, int N, class F>
__device__ __forceinline__ void unroll_for(F&& f) {
    if constexpr (J < N) { f(ic<J>{}); unroll_for<J + 1, N>(f); }
}

// ds_swizzle BitMode: dest i reads lane ((i&and)|or)^xor within 32-lane halves.
template<int PAT>
__device__ __forceinline__ int swzi(int x) { return __builtin_amdgcn_ds_swizzle(x, PAT); }
template<int PAT>
__device__ __forceinline__ float swzf(float x) { return __int_as_float(swzi<PAT>(__float_as_int(x))); }

__device__ __forceinline__ int bpermi(int addr, int x) { return __builtin_amdgcn_ds_bpermute(addr, x); }
__device__ __forceinline__ float bpermf(int addr, float x) { return __int_as_float(bpermi(addr, __float_as_int(x))); }

// DPP: row_shl:n = 0x100+n, row_shr:n = 0x110+n (16-lane rows, bound_ctrl 0-fill)
template<int CTRL>
__device__ __forceinline__ int dppi(int x) {
    return __builtin_amdgcn_update_dpp(0, x, CTRL, 0xF, 0xF, true);
}

__device__ __forceinline__ v2h pkrtz(float lo, float hi) {
    return __builtin_bit_cast(v2h, __builtin_amdgcn_cvt_pkrtz(lo, hi));
}
__device__ __forceinline__ f32x4 mfma16(v8h a, v8h b, f32x4 c) {
    return __builtin_amdgcn_mfma_f32_16x16x32_f16(a, b, c, 0, 0, 0);
}
template<int I>
__device__ __forceinline__ float xel(const f32x4& a, const f32x4& b) {
    if constexpr (I < 4) return a[I]; else return b[I - 4];
}

// R20: functional wave split -- TRUE TLP without work duplication.
// R17's trap: thinner waves duplicate wave-wide ops.  But the LSTM step
// factorizes: L1 reads {x, h1} only; L2 reads {h1, h2} only.  So:
//   A-wave (wq 0,1): L1 recurrence -- d-MFMA (K=16 live), acts, pack01,
//                    h1 -> LDS (double-buffered slot (t+1)&1).
//   B-wave (wq 2,3): L2 + output -- reads h1 slot t&1, e-MFMA, acts,
//                    pack23, ov via row-15 hijack (store out[t-1]).
// 2048 waves = 2/SIMD; per-wave issue ~halves; partner wave's issue covers
// each wave's ~200cyc recurrence-latency exposure (the ~275cyc/step stall
// measured R16-R19 that single-wave occupancy could never fill).
// h1 handoff: __syncthreads() per step (compiler drains lgkm before
// s_barrier -> cross-wave LDS visibility guaranteed).  Barrier audit:
// main 1024 + epilogue 1 + future 2x64, unconditional, all waves.
// Future phase: out->x feedback crosses waves -> 2-barrier serial
// ping-pong per step (A: x-patch,L1,h1->LDS; B: L2, outdot, ov->LDS).
// All compute components verified (R16/R19): gsel, joint-rcp acts, slots
// tree, pack, outdot butterfly, fragment maps, row-15 W_lin hijack.
__global__ __launch_bounds__(256)
__attribute__((amdgpu_waves_per_eu(2, 2)))
void lstm_seq_kernel(const float* __restrict__ input,
                     const float* __restrict__ W_ih1, const float* __restrict__ W_hh1,
                     const float* __restrict__ b_ih1, const float* __restrict__ b_hh1,
                     const float* __restrict__ W_ih2, const float* __restrict__ W_hh2,
                     const float* __restrict__ b_ih2, const float* __restrict__ b_hh2,
                     const float* __restrict__ W_lin, const float* __restrict__ b_lin,
                     float* __restrict__ out)
{
    const int tid  = threadIdx.x;
    const int wq   = tid >> 6;
    const int lane = tid & 63;
    const int u    = lane >> 4;        // K-block row / D row-group
    const int c    = lane & 15;        // MFMA col (B/D) and A-row
    const int s    = c & 3;            // sample within wave
    const int cg   = c >> 2;           // col-group == owned-unit offset
    const bool isA = (wq < 2);         // L1-wave vs L2-wave
    const int  g   = wq & 1;           // sample-group within block
    const int  b0  = (blockIdx.x * 2 + g) * 4;

    __shared__ long long hbuf[2][2][64];   // [group][slot][lane] packed {B0,B1}
    __shared__ float     ovbuf[2][4];      // [group][sample] future ov feedback

    const float L2E = 1.442695040888963f;
    const float sA[4] = {-L2E, -L2E, -2.0f * L2E, -L2E};
    const float blin = b_lin[0];

    // ---- static A fragments (chunk = gate, rows = units) + bias C ----
    v8h   A1[4], A2[4];
    f32x4 C1[4], C2[4];
    #pragma unroll
    for (int m = 0; m < 4; ++m) {
        #pragma unroll
        for (int e = 0; e < 8; ++e) {
            const int k = (e < 4) ? (4 * u + e) : (16 + 4 * u + (e - 4));
            float v1 = 0.0f, v2 = 0.0f;
            if (c < HID) {
                const int wr = m * HID + c;            // gate m, unit c
                if (k < HID)       { v1 = W_hh1[wr * HID + k]; v2 = W_ih2[wr * HID + k]; }
                else if (k == HID) { v1 = W_ih1[wr]; }                     // x slot
                else if (k >= 16 && k < 16 + HID) { v2 = W_hh2[wr * HID + (k - 16)]; }
            }
            float a2v = sA[m] * v2;
            if (c == 15 && m == 3 && k >= 16 && k < 16 + HID)
                a2v = W_lin[k - 16];                   // out-row (unscaled)
            A1[m][e] = (_Float16)(sA[m] * v1);         // k>=16 -> exact 0
            A2[m][e] = (_Float16)a2v;
        }
        #pragma unroll
        for (int r = 0; r < 4; ++r) {                  // D row 4u+r = unit 4u+r, gate m
            const int U = 4 * u + r;
            float bv1 = 0.0f, bv2 = 0.0f;
            if (U < HID) {
                bv1 = sA[m] * (b_ih1[m * HID + U] + b_hh1[m * HID + U]);
                bv2 = sA[m] * (b_ih2[m * HID + U] + b_hh2[m * HID + U]);
            }
            if (u == 3 && m == 3 && r == 3) bv2 = blin;   // out-row bias
            C1[m][r] = bv1; C2[m][r] = bv2;
        }
    }

    const int   Uown = 4 * u + cg;                     // owned unit
    const float wl2  = (Uown < HID) ? W_lin[Uown] : 0.0f;

    const bool cgb0  = (cg & 1) != 0;
    const bool cgb1  = (cg & 2) != 0;
    const bool u3b   = (u == 3);
    const int  a32   = (lane ^ 32) << 2;

    // A-wave state: own B(t) = {h1(t), x(t+1)} in B0,B1; c1
    // B-wave state: read B0r,B1r; own pack B2,B3 = h2(t-1); c2
    int B0 = 0, B1 = 0, B0r = 0, B1r = 0, B2 = 0, B3 = 0;
    float c1v = 0.0f, c2v = 0.0f, h2last = 0.0f;

    auto gsel = [&](const f32x4& q0, const f32x4& q1, const f32x4& q2, const f32x4& q3,
                    float& g0, float& g1, float& g2, float& g3) {
        auto pick = [&](const f32x4& q) -> float {
            const float t0 = cgb0 ? q[1] : q[0];
            const float t1 = cgb0 ? q[3] : q[2];
            return cgb1 ? t1 : t0;
        };
        g0 = pick(q0); g1 = pick(q1); g2 = pick(q2); g3 = pick(q3);
    };

    // joint-rcp LSTM cell update (verified R16); pad unit 15 -> h exactly 0
    auto acts = [&](float g0, float g1, float g2, float g3, float& cv) -> float {
        const float Ei = exp2_(g0);
        const float Ef = exp2_(g1);
        const float Eg = exp2_(g2);
        const float Eo = exp2_(g3);
        const float Di = 1.0f + Ei;
        const float Df = 1.0f + Ef;
        const float Dg = 1.0f + Eg;
        const float P  = Di * Dg;
        const float t  = __builtin_fmaf(-Eg, Df, Df);          // (1-Eg)*Df
        const float numer = __builtin_fmaf(cv, P, t);
        cv = numer * rcp_(P * Df);
        const float Y  = exp2_(cv * -2.885390081777927f);
        return (1.0f - Y) * rcp_((1.0f + Y) * (1.0f + Eo));
    };

    // slots: s_j = h of unit 4u+j (verified R15/R16 tree; VALU-only)
    auto slots = [&](float h, float& s0, float& s1, float& s2, float& s3) {
        const int hb = __float_as_int(h);
        const float r4  = __int_as_float(dppi<0x114>(hb) | dppi<0x10C>(hb)); // ror4
        const float r8  = __int_as_float(dppi<0x118>(hb) | dppi<0x108>(hb)); // ror8
        const float r12 = __int_as_float(dppi<0x11C>(hb) | dppi<0x104>(hb)); // ror12
        const float A0 = cgb0 ? r4  : h;
        const float A1 = cgb0 ? r12 : r8;
        const float A2 = cgb0 ? h   : r12;
        const float A3 = cgb0 ? r8  : r4;
        s0 = cgb1 ? A1 : A0;
        s1 = cgb1 ? A3 : A2;
        s2 = cgb1 ? A0 : A1;
        s3 = cgb1 ? A2 : A3;
    };

    auto pack01 = [&](float h1n, float xv) {           // A: B regs 0,1 (+x at u3)
        float s0, s1, s2, s3; slots(h1n, s0, s1, s2, s3);
        B0 = __builtin_bit_cast(int, pkrtz(s0, s1));
        B1 = __builtin_bit_cast(int, pkrtz(s2, u3b ? xv : s3));
    };
    auto pack23 = [&](float h2n) {                     // B: B regs 2,3
        float s0, s1, s2, s3; slots(h2n, s0, s1, s2, s3);
        B2 = __builtin_bit_cast(int, pkrtz(s0, s1));
        B3 = __builtin_bit_cast(int, pkrtz(s2, s3));
    };

    // out = sum over 16 unit-lanes of this sample (verified chain)
    auto outdot = [&](float h) -> float {
        float pv = wl2 * h;
        pv += swzf<0x101F>(pv);                        // xor 4
        pv += swzf<0x201F>(pv);                        // xor 8
        pv += swzf<0x401F>(pv);                        // xor 16
        pv += bpermf(a32, pv);                         // xor 32
        return pv + blin;
    };

    auto pk64 = [&](int lo, int hi) -> long long {
        return ((long long)(unsigned)hi << 32) | (unsigned)lo;
    };

    auto runL1 = [&]() -> f32x4* { return nullptr; };  // (placeholder, unused)

    const size_t xadr   = (size_t)(b0 + s) * TMAIN;    // A lanes
    const size_t outb_o = (size_t)(b0 + s) * OUTW;     // B lanes (store at cg==0)

    f32x4 xcA = {0,0,0,0}, xcB = {0,0,0,0};
    if (isA) {
        xcA = *(const f32x4*)&input[xadr];
        xcB = *(const f32x4*)&input[xadr + 4];
        // ---- A prologue: h(-1)=0; h1(0); B(0) = {h1(0), x(1)} -> slot 0 ----
        B1 = u3b ? __builtin_bit_cast(int, pkrtz(0.0f, xcA[0])) : 0;  // x(0)
        const v8h Bd = __builtin_bit_cast(v8h, (i32x4){B0, B1, 0, 0});
        f32x4 d0 = mfma16(A1[0], Bd, C1[0]);
        f32x4 d1 = mfma16(A1[1], Bd, C1[1]);
        f32x4 d2 = mfma16(A1[2], Bd, C1[2]);
        f32x4 d3 = mfma16(A1[3], Bd, C1[3]);
        float P0, P1, P2, P3;
        gsel(d0, d1, d2, d3, P0, P1, P2, P3);
        const float h1n = acts(P0, P1, P2, P3, c1v);
        pack01(h1n, xcA[1]);                           // x(1)
        hbuf[g][0][lane] = pk64(B0, B1);
    }

    // ---- main: 128 chunks x 8 steps; barrier per step ----
    #pragma unroll 1
    for (int ch = 0; ch < 128; ++ch) {
        f32x4 xnA = {0,0,0,0}, xnB = {0,0,0,0};
        if (isA) {
            const int chn = (ch < 127) ? ch + 1 : 127;  // clamp (tail x unused)
            xnA = *(const f32x4*)&input[xadr + (size_t)chn * 8];
            xnB = *(const f32x4*)&input[xadr + (size_t)chn * 8 + 4];
        }
        unroll_for<0, 8>([&](auto sc) {
            constexpr int S = decltype(sc)::v;
            __syncthreads();
            const int t = ch * 8 + S;
            if (isA) {
                // A step t: consume B(t)={h1(t),x(t+1)} -> h1(t+1); disabled at t=1023
                if ((ch < 127) || (S < 7)) {
                    const v8h Bd = __builtin_bit_cast(v8h, (i32x4){B0, B1, 0, 0});
                    f32x4 d0 = mfma16(A1[0], Bd, C1[0]);
                    f32x4 d1 = mfma16(A1[1], Bd, C1[1]);
                    f32x4 d2 = mfma16(A1[2], Bd, C1[2]);
                    f32x4 d3 = mfma16(A1[3], Bd, C1[3]);
                    float P0, P1, P2, P3;
                    gsel(d0, d1, d2, d3, P0, P1, P2, P3);
                    const float h1n = acts(P0, P1, P2, P3, c1v);
                    float xv2;
                    if constexpr (S < 6)       xv2 = xel<S + 2>(xcA, xcB);
                    else if constexpr (S == 6) xv2 = xnA[0];
                    else                       xv2 = xnA[1];
                    pack01(h1n, xv2);                  // B(t+1)
                    hbuf[g][(t + 1) & 1][lane] = pk64(B0, B1);
                }
            } else {
                // B step t: read h1(t); L2(t); ov(t-1) at e3[3]
                const long long v = hbuf[g][t & 1][lane];
                B0r = (int)(unsigned)(v & 0xFFFFFFFFll);
                B1r = (int)(unsigned)(v >> 32);
                const v8h Be = __builtin_bit_cast(v8h, (i32x4){B0r, B1r, B2, B3});
                f32x4 e0 = mfma16(A2[0], Be, C2[0]);
                f32x4 e1 = mfma16(A2[1], Be, C2[1]);
                f32x4 e2 = mfma16(A2[2], Be, C2[2]);
                f32x4 e3 = mfma16(A2[3], Be, C2[3]);
                if (t > 0 && u3b && cg == 0)
                    out[outb_o + (t - 1)] = e3[3];     // ov(t-1)
                float Q0, Q1, Q2, Q3;
                gsel(e0, e1, e2, e3, Q0, Q1, Q2, Q3);
                h2last = acts(Q0, Q1, Q2, Q3, c2v);    // h2(t)
                pack23(h2last);                        // B2,B3 for step t+1
            }
        });
        if (isA) { xcA = xnA; xcB = xnB; }
    }

    // ---- epilogue: ov(1023) from h2(1023); seed future feedback ----
    __syncthreads();
    if (!isA) {
        const float ov23 = outdot(h2last);
        if (lane < 4) {
            ovbuf[g][lane] = ov23;                     // sample = lane
            out[(size_t)(b0 + lane) * OUTW + (TMAIN - 1)] = ov23;
        }
    }

    // ---- future: 64 steps, 2-barrier ping-pong (A: L1 | B: L2+ov) ----
    #pragma unroll 1
    for (int f = 0; f < FUT; ++f) {
        const int t = TMAIN + f;
        __syncthreads();                               // ovbuf[t-1] visible
        if (isA) {
            const float ovp = ovbuf[g][s];             // x(t) = ov(t-1)
            const int xb = __builtin_bit_cast(int, pkrtz(0.0f, ovp)) & 0xFFFF0000;
            B1 = u3b ? ((B1 & 0xFFFF) | xb) : B1;
            const v8h Bd = __builtin_bit_cast(v8h, (i32x4){B0, B1, 0, 0});
            f32x4 d0 = mfma16(A1[0], Bd, C1[0]);
            f32x4 d1 = mfma16(A1[1], Bd, C1[1]);
            f32x4 d2 = mfma16(A1[2], Bd, C1[2]);
            f32x4 d3 = mfma16(A1[3], Bd, C1[3]);
            float P0, P1, P2, P3;
            gsel(d0, d1, d2, d3, P0, P1, P2, P3);
            const float h1n = acts(P0, P1, P2, P3, c1v);
            pack01(h1n, 0.0f);                         // x patched next iter
            hbuf[g][t & 1][lane] = pk64(B0, B1);
        }
        __syncthreads();                               // h1(t) visible
        if (!isA) {
            const long long v = hbuf[g][t & 1][lane];
            B0r = (int)(unsigned)(v & 0xFFFFFFFFll);
            B1r = (int)(unsigned)(v >> 32);
            const v8h Be = __builtin_bit_cast(v8h, (i32x4){B0r, B1r, B2, B3});
            f32x4 e0 = mfma16(A2[0], Be, C2[0]);
            f32x4 e1 = mfma16(A2[1], Be, C2[1]);
            f32x4 e2 = mfma16(A2[2], Be, C2[2]);
            f32x4 e3 = mfma16(A2[3], Be, C2[3]);
            float Q0, Q1, Q2, Q3;
            gsel(e0, e1, e2, e3, Q0, Q1, Q2, Q3);
            const float h2n = acts(Q0, Q1, Q2, Q3, c2v);
            const float ov = outdot(h2n);              // ov(t)
            pack23(h2n);
            if (lane < 4) {
                ovbuf[g][lane] = ov;
                out[(size_t)(b0 + lane) * OUTW + t] = ov;
            }
        }
    }
}

extern "C" void kernel_launch(void* const* d_in, const int* in_sizes, int n_in,
                              void* d_out, int out_size, void* d_ws, size_t ws_size,
                              hipStream_t stream)
{
    const float* input = (const float*)d_in[0];
    const float* W_ih1 = (const float*)d_in[1];
    const float* W_hh1 = (const float*)d_in[2];
    const float* b_ih1 = (const float*)d_in[3];
    const float* b_hh1 = (const float*)d_in[4];
    const float* W_ih2 = (const float*)d_in[5];
    const float* W_hh2 = (const float*)d_in[6];
    const float* b_ih2 = (const float*)d_in[7];
    const float* b_hh2 = (const float*)d_in[8];
    const float* W_lin = (const float*)d_in[9];
    const float* b_lin = (const float*)d_in[10];
    // d_in[11] = future (=64), compiled in as FUT

    // 4096 samples / (4 per group * 2 groups per block) = 512 blocks;
    // each block: 2 A-waves (L1) + 2 B-waves (L2) -> 2048 waves = 2/SIMD
    lstm_seq_kernel<<<512, 256, 0, stream>>>(
        input, W_ih1, W_hh1, b_ih1, b_hh1,
        W_ih2, W_hh2, b_ih2, b_hh2, W_lin, b_lin,
        (float*)d_out);
}